// Round 1
// baseline (633.944 us; speedup 1.0000x reference)
//
#include <hip/hip_runtime.h>
#include <hip/hip_bf16.h>

// Problem constants (B=2, T=2048, C=2048, NH=16, L=128)
#define B_   2
#define T_   2048
#define C_   2048
#define NH_  16
#define L_   128
#define NKQ  2176   // L_ + NH_*L_
#define MTOK 4096   // B_*T_

typedef short short8 __attribute__((ext_vector_type(8)));
typedef float f32x4  __attribute__((ext_vector_type(4)));

__device__ __forceinline__ unsigned short f2bf(float f) {
  union { float f; unsigned u; } x; x.f = f;
  unsigned r = x.u + 0x7fffu + ((x.u >> 16) & 1u);   // RNE
  return (unsigned short)(r >> 16);
}

// ---------------- fp32 -> bf16 convert (n % 4 == 0) ----------------
__global__ void cvt_f32_bf16(const float* __restrict__ in,
                             unsigned short* __restrict__ out, int n) {
  int i = (blockIdx.x * blockDim.x + threadIdx.x) * 4;
  if (i >= n) return;
  float4 v = *(const float4*)(in + i);
  ushort4 o;
  o.x = f2bf(v.x); o.y = f2bf(v.y); o.z = f2bf(v.z); o.w = f2bf(v.w);
  *(ushort4*)(out + i) = o;
}

// ------------- transpose W[K][N] fp32 -> Wt[N][K] bf16 -------------
__global__ void transpose_to_bf16(const float* __restrict__ W,
                                  unsigned short* __restrict__ Wt,
                                  int K, int N) {
  __shared__ float tile[32][33];
  int bx = blockIdx.x * 32;  // along N
  int by = blockIdx.y * 32;  // along K
  int tx = threadIdx.x, ty = threadIdx.y;
  #pragma unroll
  for (int i = 0; i < 4; i++)
    tile[ty + i * 8][tx] = W[(size_t)(by + ty + i * 8) * N + bx + tx];
  __syncthreads();
  #pragma unroll
  for (int i = 0; i < 4; i++)
    Wt[(size_t)(bx + ty + i * 8) * K + by + tx] = f2bf(tile[tx][ty + i * 8]);
}

// ---------------- concat bias [b_lat | b_d] ----------------
__global__ void make_bias_cat(const float* __restrict__ b_lat,
                              const float* __restrict__ b_d,
                              float* __restrict__ out) {
  int i = blockIdx.x * blockDim.x + threadIdx.x;
  if (i < L_) out[i] = b_lat[i];
  else if (i < NKQ) out[i] = b_d[i - L_];
}

// ---------------- bf16 MFMA GEMM:  C = A[M,K] @ Bt[N,K]^T + bias ----------------
// 128x128 tile, BK=32, 256 threads = 4 waves, each wave 64x64 (4x4 of 16x16x32).
__global__ __launch_bounds__(256) void gemm_bt_bias(
    const unsigned short* __restrict__ A,   // [M][K] bf16
    const unsigned short* __restrict__ Bt,  // [N][K] bf16
    const float* __restrict__ bias,         // [N]
    unsigned short* __restrict__ Cb,        // bf16 out (or null)
    float* __restrict__ Cf,                 // fp32 out (or null)
    int M, int N, int K) {
  __shared__ unsigned short As[128 * 40];  // +8 pad per row
  __shared__ unsigned short Bs[128 * 40];
  const int tid  = threadIdx.x;
  const int wave = tid >> 6, lane = tid & 63;
  const int lcol = lane & 15, quad = lane >> 4;
  const int m0 = blockIdx.x * 128, n0 = blockIdx.y * 128;
  const int wm = (wave >> 1) * 64, wn = (wave & 1) * 64;

  f32x4 acc[4][4];
  #pragma unroll
  for (int i = 0; i < 4; i++)
    #pragma unroll
    for (int j = 0; j < 4; j++) acc[i][j] = (f32x4){0.f, 0.f, 0.f, 0.f};

  for (int kc = 0; kc < K; kc += 32) {
    __syncthreads();
    {  // stage 128x32 A and Bt tiles: 512 chunks of 8 bf16, 2 per thread
      int r0 = tid >> 2, q0 = (tid & 3) * 8;
      *(short8*)&As[r0 * 40 + q0] = *(const short8*)&A[(size_t)(m0 + r0) * K + kc + q0];
      *(short8*)&Bs[r0 * 40 + q0] = *(const short8*)&Bt[(size_t)(n0 + r0) * K + kc + q0];
      int c1 = tid + 256;
      int r1 = c1 >> 2, q1 = (c1 & 3) * 8;
      *(short8*)&As[r1 * 40 + q1] = *(const short8*)&A[(size_t)(m0 + r1) * K + kc + q1];
      *(short8*)&Bs[r1 * 40 + q1] = *(const short8*)&Bt[(size_t)(n0 + r1) * K + kc + q1];
    }
    __syncthreads();
    short8 af[4], bfr[4];
    #pragma unroll
    for (int i = 0; i < 4; i++)
      af[i] = *(const short8*)&As[(wm + i * 16 + lcol) * 40 + quad * 8];
    #pragma unroll
    for (int j = 0; j < 4; j++)
      bfr[j] = *(const short8*)&Bs[(wn + j * 16 + lcol) * 40 + quad * 8];
    #pragma unroll
    for (int i = 0; i < 4; i++)
      #pragma unroll
      for (int j = 0; j < 4; j++)
        acc[i][j] = __builtin_amdgcn_mfma_f32_16x16x32_bf16(af[i], bfr[j], acc[i][j], 0, 0, 0);
  }

  // epilogue: C/D layout col=lane&15, row=quad*4+reg
  #pragma unroll
  for (int i = 0; i < 4; i++) {
    #pragma unroll
    for (int j = 0; j < 4; j++) {
      int col = n0 + wn + j * 16 + lcol;
      float bv = bias[col];
      #pragma unroll
      for (int r = 0; r < 4; r++) {
        int row = m0 + wm + i * 16 + quad * 4 + r;
        float v = acc[i][j][r] + bv;
        if (Cf) Cf[(size_t)row * N + col] = v;
        else    Cb[(size_t)row * N + col] = f2bf(v);
      }
    }
  }
}

// ---------------- fused causal attention on the shared latent ----------------
// kq: [B*T][NKQ] bf16, cols [0,128) = latent k (=K=V), cols 128+h*128+l = q.
// One block = 64 q-rows (4 waves x 16), one (b,h). Iterate s-tiles of 64.
__global__ __launch_bounds__(256) void attn_mla(
    const unsigned short* __restrict__ kq,
    unsigned short* __restrict__ y) {         // [B*T][NH*L] bf16
  __shared__ unsigned short Kr[64 * 136];     // K row-major [s][L], pad 136
  __shared__ unsigned short Kt[128 * 72];     // K transposed [L][s], pad 72
  __shared__ unsigned short Pls[4][16 * 72];  // per-wave P [16][64], pad 72

  const int tid  = threadIdx.x;
  const int wave = tid >> 6, lane = tid & 63;
  const int lcol = lane & 15, quad = lane >> 4;
  const int blkq = blockIdx.x;                // q-tile (64 rows)
  const int bh   = blockIdx.y;
  const int b = bh >> 4, h = bh & 15;
  const size_t rowbase = (size_t)b * T_;
  const int q0w = blkq * 64 + wave * 16;      // this wave's first q row
  const float scale = 0.08838834764831845f;   // 1/sqrt(128)

  // Q fragments: A-layout m=lane&15, k=quad*8+j ; 4 chunks of k=32
  short8 qf[4];
  {
    const unsigned short* qptr = kq + (rowbase + q0w + lcol) * NKQ + L_ + h * L_;
    #pragma unroll
    for (int kc = 0; kc < 4; kc++)
      qf[kc] = *(const short8*)(qptr + kc * 32 + quad * 8);
  }

  f32x4 acco[8];
  #pragma unroll
  for (int i = 0; i < 8; i++) acco[i] = (f32x4){0.f, 0.f, 0.f, 0.f};
  float mrun[4], lrun[4];
  #pragma unroll
  for (int r = 0; r < 4; r++) { mrun[r] = -1e30f; lrun[r] = 0.f; }

  const int ntiles = blkq + 1;
  for (int ts = 0; ts < ntiles; ts++) {
    const int s0 = ts * 64;
    __syncthreads();
    // stage K tile 64x128 into both layouts
    #pragma unroll
    for (int it = 0; it < 4; it++) {
      int c = tid + it * 256;              // 1024 chunks of 8
      int r = c >> 4, q = (c & 15) * 8;
      short8 v = *(const short8*)&kq[(rowbase + s0 + r) * NKQ + q];
      *(short8*)&Kr[r * 136 + q] = v;
      #pragma unroll
      for (int j = 0; j < 8; j++) Kt[(q + j) * 72 + r] = (unsigned short)v[j];
    }
    __syncthreads();

    // S(16x64) = Q(16x128) @ K^T : B[k][n] = Kr[n][k]
    f32x4 accs[4];
    #pragma unroll
    for (int ns = 0; ns < 4; ns++) accs[ns] = (f32x4){0.f, 0.f, 0.f, 0.f};
    #pragma unroll
    for (int kc = 0; kc < 4; kc++)
      #pragma unroll
      for (int ns = 0; ns < 4; ns++) {
        short8 bfrag = *(const short8*)&Kr[(ns * 16 + lcol) * 136 + kc * 32 + quad * 8];
        accs[ns] = __builtin_amdgcn_mfma_f32_16x16x32_bf16(qf[kc], bfrag, accs[ns], 0, 0, 0);
      }

    // masked scale + online softmax (rows = quad*4+r, cols = ns*16+lcol)
    float p[4][4];
    float tmax[4] = {-1e30f, -1e30f, -1e30f, -1e30f};
    #pragma unroll
    for (int ns = 0; ns < 4; ns++)
      #pragma unroll
      for (int r = 0; r < 4; r++) {
        float v = accs[ns][r] * scale;
        int sg = s0 + ns * 16 + lcol;
        int qg = q0w + quad * 4 + r;
        v = (sg <= qg) ? v : -1e30f;
        p[ns][r] = v;
        tmax[r] = fmaxf(tmax[r], v);
      }
    #pragma unroll
    for (int off = 1; off < 16; off <<= 1)
      #pragma unroll
      for (int r = 0; r < 4; r++)
        tmax[r] = fmaxf(tmax[r], __shfl_xor(tmax[r], off, 64));
    float alpha[4], tsum[4];
    #pragma unroll
    for (int r = 0; r < 4; r++) {
      float mn = fmaxf(mrun[r], tmax[r]);
      alpha[r] = __expf(mrun[r] - mn);
      mrun[r] = mn;
      tsum[r] = 0.f;
    }
    #pragma unroll
    for (int ns = 0; ns < 4; ns++)
      #pragma unroll
      for (int r = 0; r < 4; r++) {
        float e = __expf(p[ns][r] - mrun[r]);
        p[ns][r] = e;
        tsum[r] += e;
      }
    #pragma unroll
    for (int off = 1; off < 16; off <<= 1)
      #pragma unroll
      for (int r = 0; r < 4; r++)
        tsum[r] += __shfl_xor(tsum[r], off, 64);
    #pragma unroll
    for (int r = 0; r < 4; r++) lrun[r] = lrun[r] * alpha[r] + tsum[r];

    // rescale O accumulator
    #pragma unroll
    for (int ns = 0; ns < 8; ns++)
      #pragma unroll
      for (int r = 0; r < 4; r++) acco[ns][r] *= alpha[r];

    // P -> LDS (C-layout to A-layout round trip), bf16
    unsigned short* Pw = &Pls[wave][0];
    #pragma unroll
    for (int ns = 0; ns < 4; ns++)
      #pragma unroll
      for (int r = 0; r < 4; r++)
        Pw[(quad * 4 + r) * 72 + ns * 16 + lcol] = f2bf(p[ns][r]);

    // O(16x128) += P(16x64) @ K(64x128) : B[k][n] = Kt[n][k]
    #pragma unroll
    for (int kc2 = 0; kc2 < 2; kc2++) {
      short8 pa = *(const short8*)&Pw[lcol * 72 + kc2 * 32 + quad * 8];
      #pragma unroll
      for (int ns = 0; ns < 8; ns++) {
        short8 bfrag = *(const short8*)&Kt[(ns * 16 + lcol) * 72 + kc2 * 32 + quad * 8];
        acco[ns] = __builtin_amdgcn_mfma_f32_16x16x32_bf16(pa, bfrag, acco[ns], 0, 0, 0);
      }
    }
  }

  // normalize and write y (bf16)
  float inv[4];
  #pragma unroll
  for (int r = 0; r < 4; r++) inv[r] = 1.f / lrun[r];
  #pragma unroll
  for (int ns = 0; ns < 8; ns++)
    #pragma unroll
    for (int r = 0; r < 4; r++) {
      int qg = q0w + quad * 4 + r;
      y[(rowbase + qg) * (NH_ * L_) + h * L_ + ns * 16 + lcol] = f2bf(acco[ns][r] * inv[r]);
    }
}

extern "C" void kernel_launch(void* const* d_in, const int* in_sizes, int n_in,
                              void* d_out, int out_size, void* d_ws, size_t ws_size,
                              hipStream_t stream) {
  const float* x      = (const float*)d_in[0];
  const float* W_lat  = (const float*)d_in[1];
  const float* b_lat  = (const float*)d_in[2];
  const float* W_d    = (const float*)d_in[3];
  const float* b_d    = (const float*)d_in[4];
  const float* W_proj = (const float*)d_in[5];
  const float* b_proj = (const float*)d_in[6];
  float* out = (float*)d_out;

  // workspace layout (bf16 buffers, all 16B aligned)
  unsigned short* x_bf   = (unsigned short*)d_ws;                  // [4096][2048]
  unsigned short* BtCat  = x_bf   + (size_t)MTOK * C_;             // [2176][2048]
  unsigned short* WprojT = BtCat  + (size_t)NKQ * C_;              // [2048][2048]
  unsigned short* kqbuf  = WprojT + (size_t)C_ * (NH_ * L_);       // [4096][2176]
  unsigned short* ybuf   = kqbuf  + (size_t)MTOK * NKQ;            // [4096][2048]
  float*          biascat = (float*)(ybuf + (size_t)MTOK * (NH_ * L_)); // [2176]

  // 1. x -> bf16
  cvt_f32_bf16<<<(MTOK * C_) / 1024, 256, 0, stream>>>(x, x_bf, MTOK * C_);
  // 2. weights -> transposed bf16 (Bt layout, K contiguous)
  transpose_to_bf16<<<dim3(L_ / 32, C_ / 32), dim3(32, 8), 0, stream>>>(W_lat, BtCat, C_, L_);
  transpose_to_bf16<<<dim3((NH_ * L_) / 32, C_ / 32), dim3(32, 8), 0, stream>>>(
      W_d, BtCat + (size_t)L_ * C_, C_, NH_ * L_);
  transpose_to_bf16<<<dim3(C_ / 32, (NH_ * L_) / 32), dim3(32, 8), 0, stream>>>(
      W_proj, WprojT, NH_ * L_, C_);
  make_bias_cat<<<(NKQ + 255) / 256, 256, 0, stream>>>(b_lat, b_d, biascat);
  // 3. fused latent+q GEMM: kq = x @ [W_lat | W_d] + [b_lat | b_d]  (bf16 out)
  gemm_bt_bias<<<dim3(MTOK / 128, NKQ / 128), 256, 0, stream>>>(
      x_bf, BtCat, biascat, kqbuf, nullptr, MTOK, NKQ, C_);
  // 4. causal MLA attention (K=V=latent, shared across heads)
  attn_mla<<<dim3(T_ / 64, B_ * NH_), 256, 0, stream>>>(kqbuf, ybuf);
  // 5. output projection: out = y @ W_proj + b_proj (fp32 out)
  gemm_bt_bias<<<dim3(MTOK / 128, C_ / 128), 256, 0, stream>>>(
      ybuf, WprojT, b_proj, nullptr, out, MTOK, C_, C_);
}

// Round 2
// 351.614 us; speedup vs baseline: 1.8030x; 1.8030x over previous
//
#include <hip/hip_runtime.h>
#include <hip/hip_bf16.h>

// Problem constants (B=2, T=2048, C=2048, NH=16, L=128)
#define B_   2
#define T_   2048
#define C_   2048
#define NH_  16
#define L_   128
#define NKQ  2176   // L_ + NH_*L_
#define MTOK 4096   // B_*T_
#define SCALE_ 0.08838834764831845f  // 1/sqrt(128)

typedef short short8 __attribute__((ext_vector_type(8)));
typedef float f32x4  __attribute__((ext_vector_type(4)));

// async global->LDS, 16B per lane; LDS base must be wave-uniform.
#define GLD16(gp, lp) __builtin_amdgcn_global_load_lds(                      \
    (const __attribute__((address_space(1))) void*)(gp),                     \
    (__attribute__((address_space(3))) void*)(lp), 16, 0, 0)

__device__ __forceinline__ unsigned short f2bf(float f) {
  union { float f; unsigned u; } x; x.f = f;
  unsigned r = x.u + 0x7fffu + ((x.u >> 16) & 1u);   // RNE
  return (unsigned short)(r >> 16);
}

// ---------------- fp32 -> bf16 convert (n % 4 == 0) ----------------
__global__ void cvt_f32_bf16(const float* __restrict__ in,
                             unsigned short* __restrict__ out, int n) {
  int i = (blockIdx.x * blockDim.x + threadIdx.x) * 4;
  if (i >= n) return;
  float4 v = *(const float4*)(in + i);
  ushort4 o;
  o.x = f2bf(v.x); o.y = f2bf(v.y); o.z = f2bf(v.z); o.w = f2bf(v.w);
  *(ushort4*)(out + i) = o;
}

// ------------- transpose W[K][N] fp32 -> Wt[N][K] bf16 (x mul) -------------
__global__ void transpose_to_bf16(const float* __restrict__ W,
                                  unsigned short* __restrict__ Wt,
                                  int K, int N, float mul) {
  __shared__ float tile[32][33];
  int bx = blockIdx.x * 32;  // along N
  int by = blockIdx.y * 32;  // along K
  int tx = threadIdx.x, ty = threadIdx.y;
  #pragma unroll
  for (int i = 0; i < 4; i++)
    tile[ty + i * 8][tx] = W[(size_t)(by + ty + i * 8) * N + bx + tx];
  __syncthreads();
  #pragma unroll
  for (int i = 0; i < 4; i++)
    Wt[(size_t)(bx + ty + i * 8) * K + by + tx] = f2bf(tile[tx][ty + i * 8] * mul);
}

// ---- transpose latent cols of kq -> KlT[b][l][t] (bf16) ----
__global__ void transpose_lat(const unsigned short* __restrict__ kq,
                              unsigned short* __restrict__ KlT) {
  __shared__ unsigned short tile[32][33];
  int t0 = blockIdx.x * 32, l0 = blockIdx.y * 32, b = blockIdx.z;
  int tx = threadIdx.x, ty = threadIdx.y;
  #pragma unroll
  for (int i = 0; i < 4; i++)
    tile[ty + i * 8][tx] = kq[((size_t)b * T_ + t0 + ty + i * 8) * NKQ + l0 + tx];
  __syncthreads();
  #pragma unroll
  for (int i = 0; i < 4; i++)
    KlT[((size_t)b * L_ + l0 + ty + i * 8) * T_ + t0 + tx] = tile[tx][ty + i * 8];
}

// ---------------- concat bias [b_lat | scale*b_d] ----------------
__global__ void make_bias_cat(const float* __restrict__ b_lat,
                              const float* __restrict__ b_d,
                              float* __restrict__ out) {
  int i = blockIdx.x * blockDim.x + threadIdx.x;
  if (i < L_) out[i] = b_lat[i];
  else if (i < NKQ) out[i] = b_d[i - L_] * SCALE_;
}

// ---------------- bf16 MFMA GEMM (m97 structure):  C = A @ Bt^T + bias ----------------
__global__ __launch_bounds__(256) void gemm_bt_bias(
    const unsigned short* __restrict__ A,   // [M][K] bf16
    const unsigned short* __restrict__ Bt,  // [N][K] bf16
    const float* __restrict__ bias,         // [N]
    unsigned short* __restrict__ Cb,        // bf16 out (or null)
    float* __restrict__ Cf,                 // fp32 out (or null)
    int M, int N, int K) {
  __shared__ __align__(16) unsigned short As[128 * 32];  // unpadded, BK=32
  __shared__ __align__(16) unsigned short Bs[128 * 32];
  const int tid  = threadIdx.x;
  const int wave = tid >> 6, lane = tid & 63;
  const int lcol = lane & 15, quad = lane >> 4;
  const int m0 = blockIdx.x * 128, n0 = blockIdx.y * 128;
  const int wm = (wave >> 1) * 64, wn = (wave & 1) * 64;
  const int lrow = lane >> 2, lchunk = (lane & 3) * 8;

  f32x4 acc[4][4];
  #pragma unroll
  for (int i = 0; i < 4; i++)
    #pragma unroll
    for (int j = 0; j < 4; j++) acc[i][j] = (f32x4){0.f, 0.f, 0.f, 0.f};

  for (int kc = 0; kc < K; kc += 32) {
    __syncthreads();
    {
      int rb = wave * 32;
      GLD16(&A [(size_t)(m0 + rb      + lrow) * K + kc + lchunk], &As[ rb       * 32]);
      GLD16(&A [(size_t)(m0 + rb + 16 + lrow) * K + kc + lchunk], &As[(rb + 16) * 32]);
      GLD16(&Bt[(size_t)(n0 + rb      + lrow) * K + kc + lchunk], &Bs[ rb       * 32]);
      GLD16(&Bt[(size_t)(n0 + rb + 16 + lrow) * K + kc + lchunk], &Bs[(rb + 16) * 32]);
    }
    __syncthreads();
    short8 af[4], bfr[4];
    #pragma unroll
    for (int i = 0; i < 4; i++)
      af[i] = *(const short8*)&As[(wm + i * 16 + lcol) * 32 + quad * 8];
    #pragma unroll
    for (int j = 0; j < 4; j++)
      bfr[j] = *(const short8*)&Bs[(wn + j * 16 + lcol) * 32 + quad * 8];
    #pragma unroll
    for (int i = 0; i < 4; i++)
      #pragma unroll
      for (int j = 0; j < 4; j++)
        acc[i][j] = __builtin_amdgcn_mfma_f32_16x16x32_bf16(af[i], bfr[j], acc[i][j], 0, 0, 0);
  }

  #pragma unroll
  for (int i = 0; i < 4; i++) {
    #pragma unroll
    for (int j = 0; j < 4; j++) {
      int col = n0 + wn + j * 16 + lcol;
      float bv = bias[col];
      #pragma unroll
      for (int r = 0; r < 4; r++) {
        int row = m0 + wm + i * 16 + quad * 4 + r;
        float v = acc[i][j][r] + bv;
        if (Cf) Cf[(size_t)row * N + col] = v;
        else    Cb[(size_t)row * N + col] = f2bf(v);
      }
    }
  }
}

// ---------------- fused causal MLA attention ----------------
// Block: 4 waves; wave w = head hg*4+w, 64 q-rows. s-tiles of 64.
// No-max softmax (scores are O(1); scale folded into q at projection).
// LDS layouts XOR-swizzled: phys_chunk = chunk ^ (row&7), rows unpadded.
__global__ __launch_bounds__(256, 1) void attn_mla(
    const unsigned short* __restrict__ kq,   // [B*T][NKQ]
    const unsigned short* __restrict__ KlT,  // [B][L][T]
    unsigned short* __restrict__ y) {        // [B*T][NH*L]
  __shared__ __align__(16) unsigned short Kr[64 * 128];   // [s][l] swizzled
  __shared__ __align__(16) unsigned short Kt[128 * 64];   // [l][s] swizzled
  __shared__ __align__(16) unsigned short Pls[4 * 64 * 64];  // per-wave P, swizzled

  const int tid  = threadIdx.x;
  const int wave = tid >> 6, lane = tid & 63;
  const int lcol = lane & 15, quad = lane >> 4;
  const int qt = blockIdx.x;            // q-tile (64 rows)
  const int b  = blockIdx.y >> 2, hg = blockIdx.y & 3;
  const int h  = hg * 4 + wave;
  const size_t rowbase = (size_t)b * T_;
  const int q0 = qt * 64;
  unsigned short* Pw = &Pls[wave * 64 * 64];

  // Q fragments (A-layout m=lane&15, k=quad*8+j), scale pre-folded
  short8 qf[4][4];
  #pragma unroll
  for (int i = 0; i < 4; i++) {
    const unsigned short* qp = kq + (rowbase + q0 + i * 16 + lcol) * NKQ + L_ + h * L_;
    #pragma unroll
    for (int kc = 0; kc < 4; kc++)
      qf[i][kc] = *(const short8*)(qp + kc * 32 + quad * 8);
  }

  f32x4 acco[4][8];
  #pragma unroll
  for (int i = 0; i < 4; i++)
    #pragma unroll
    for (int ns = 0; ns < 8; ns++) acco[i][ns] = (f32x4){0.f, 0.f, 0.f, 0.f};
  float lsum[4][4];
  #pragma unroll
  for (int i = 0; i < 4; i++)
    #pragma unroll
    for (int r = 0; r < 4; r++) lsum[i][r] = 0.f;

  const int nt = qt + 1;
  for (int ts = 0; ts < nt; ts++) {
    const int s0 = ts * 64;
    __syncthreads();
    // stage Kr (64x128): 16 instrs of 4 rows; swizzled source chunk
    #pragma unroll
    for (int kk = 0; kk < 4; kk++) {
      int r0 = wave * 16 + kk * 4;
      int rg = r0 + (lane >> 4);
      int cl = ((lane & 15) ^ (rg & 7)) * 8;
      GLD16(kq + (rowbase + s0 + rg) * NKQ + cl, &Kr[r0 * 128]);
    }
    // stage Kt (128x64) from KlT: 16 instrs of 8 rows
    #pragma unroll
    for (int kk = 0; kk < 4; kk++) {
      int r0 = wave * 32 + kk * 8;
      int rg = r0 + (lane >> 3);
      int cl = ((lane & 7) ^ (rg & 7)) * 8;
      GLD16(KlT + ((size_t)b * L_ + rg) * T_ + s0 + cl, &Kt[r0 * 64]);
    }
    __syncthreads();

    // S(64x64) = Q @ K^T
    f32x4 accs[4][4];
    #pragma unroll
    for (int i = 0; i < 4; i++)
      #pragma unroll
      for (int ns = 0; ns < 4; ns++) accs[i][ns] = (f32x4){0.f, 0.f, 0.f, 0.f};
    #pragma unroll
    for (int kc = 0; kc < 4; kc++)
      #pragma unroll
      for (int ns = 0; ns < 4; ns++) {
        short8 bfrag = *(const short8*)&Kr[(ns * 16 + lcol) * 128 +
                                           (((kc * 4 + quad) ^ (lcol & 7)) * 8)];
        #pragma unroll
        for (int i = 0; i < 4; i++)
          accs[i][ns] = __builtin_amdgcn_mfma_f32_16x16x32_bf16(qf[i][kc], bfrag, accs[i][ns], 0, 0, 0);
      }

    // p = exp(s) (no max subtraction), mask only on diagonal tile
    const bool diag = (ts == qt);
    #pragma unroll
    for (int i = 0; i < 4; i++)
      #pragma unroll
      for (int ns = 0; ns < 4; ns++)
        #pragma unroll
        for (int r = 0; r < 4; r++) {
          float v = accs[i][ns][r];
          if (diag) {
            int sg = ns * 16 + lcol;              // relative: s0 == q0 here
            int qg = i * 16 + quad * 4 + r;
            if (sg > qg) v = -1e30f;
          }
          float e = __expf(v);
          lsum[i][r] += e;
          int row = i * 16 + quad * 4 + r;
          int col = ns * 16 + lcol;
          int phys = ((col >> 3) ^ (row & 7));
          Pw[row * 64 + phys * 8 + (col & 7)] = f2bf(e);
        }

    // O(64x128) += P(64x64) @ K(64x128)
    #pragma unroll
    for (int kc2 = 0; kc2 < 2; kc2++) {
      short8 pa[4];
      #pragma unroll
      for (int i = 0; i < 4; i++)
        pa[i] = *(const short8*)&Pw[(i * 16 + lcol) * 64 +
                                    (((kc2 * 4 + quad) ^ (lcol & 7)) * 8)];
      #pragma unroll
      for (int ns = 0; ns < 8; ns++) {
        short8 bfrag = *(const short8*)&Kt[(ns * 16 + lcol) * 64 +
                                           (((kc2 * 4 + quad) ^ (lcol & 7)) * 8)];
        #pragma unroll
        for (int i = 0; i < 4; i++)
          acco[i][ns] = __builtin_amdgcn_mfma_f32_16x16x32_bf16(pa[i], bfrag, acco[i][ns], 0, 0, 0);
      }
    }
  }

  // reduce row sums across the 16 lcol lanes (once)
  #pragma unroll
  for (int i = 0; i < 4; i++)
    #pragma unroll
    for (int r = 0; r < 4; r++) {
      float s = lsum[i][r];
      #pragma unroll
      for (int off = 1; off < 16; off <<= 1) s += __shfl_xor(s, off, 64);
      lsum[i][r] = 1.f / s;
    }

  // write y
  #pragma unroll
  for (int i = 0; i < 4; i++)
    #pragma unroll
    for (int ns = 0; ns < 8; ns++)
      #pragma unroll
      for (int r = 0; r < 4; r++) {
        int qg = q0 + i * 16 + quad * 4 + r;
        y[(rowbase + qg) * (NH_ * L_) + h * L_ + ns * 16 + lcol] =
            f2bf(acco[i][ns][r] * lsum[i][r]);
      }
}

extern "C" void kernel_launch(void* const* d_in, const int* in_sizes, int n_in,
                              void* d_out, int out_size, void* d_ws, size_t ws_size,
                              hipStream_t stream) {
  const float* x      = (const float*)d_in[0];
  const float* W_lat  = (const float*)d_in[1];
  const float* b_lat  = (const float*)d_in[2];
  const float* W_d    = (const float*)d_in[3];
  const float* b_d    = (const float*)d_in[4];
  const float* W_proj = (const float*)d_in[5];
  const float* b_proj = (const float*)d_in[6];
  float* out = (float*)d_out;

  // workspace layout (bf16 buffers, 16B aligned)
  unsigned short* x_bf   = (unsigned short*)d_ws;                  // [4096][2048]
  unsigned short* BtCat  = x_bf   + (size_t)MTOK * C_;             // [2176][2048]
  unsigned short* WprojT = BtCat  + (size_t)NKQ * C_;              // [2048][2048]
  unsigned short* kqbuf  = WprojT + (size_t)C_ * (NH_ * L_);       // [4096][2176]
  unsigned short* ybuf   = kqbuf  + (size_t)MTOK * NKQ;            // [4096][2048]
  unsigned short* KlT    = ybuf   + (size_t)MTOK * (NH_ * L_);     // [2][128][2048]
  float*          biascat = (float*)(KlT + (size_t)B_ * L_ * T_);  // [2176]

  // 1. x -> bf16
  cvt_f32_bf16<<<(MTOK * C_) / 1024, 256, 0, stream>>>(x, x_bf, MTOK * C_);
  // 2. weights -> transposed bf16 (Bt layout); fold softmax scale into W_d
  transpose_to_bf16<<<dim3(L_ / 32, C_ / 32), dim3(32, 8), 0, stream>>>(W_lat, BtCat, C_, L_, 1.f);
  transpose_to_bf16<<<dim3((NH_ * L_) / 32, C_ / 32), dim3(32, 8), 0, stream>>>(
      W_d, BtCat + (size_t)L_ * C_, C_, NH_ * L_, SCALE_);
  transpose_to_bf16<<<dim3(C_ / 32, (NH_ * L_) / 32), dim3(32, 8), 0, stream>>>(
      W_proj, WprojT, NH_ * L_, C_, 1.f);
  make_bias_cat<<<(NKQ + 255) / 256, 256, 0, stream>>>(b_lat, b_d, biascat);
  // 3. kq = x @ [W_lat | scale*W_d] + bias (bf16 out)
  gemm_bt_bias<<<dim3(MTOK / 128, NKQ / 128), 256, 0, stream>>>(
      x_bf, BtCat, biascat, kqbuf, nullptr, MTOK, NKQ, C_);
  // 4. latent transpose for PV staging
  transpose_lat<<<dim3(T_ / 32, L_ / 32, B_), dim3(32, 8), 0, stream>>>(kqbuf, KlT);
  // 5. causal MLA attention
  attn_mla<<<dim3(T_ / 64, B_ * 4), 256, 0, stream>>>(kqbuf, KlT, ybuf);
  // 6. out = y @ W_proj + b_proj (fp32 out)
  gemm_bt_bias<<<dim3(MTOK / 128, C_ / 128), 256, 0, stream>>>(
      ybuf, WprojT, b_proj, nullptr, out, MTOK, C_, C_);
}

// Round 3
// 309.424 us; speedup vs baseline: 2.0488x; 1.1364x over previous
//
#include <hip/hip_runtime.h>
#include <hip/hip_bf16.h>

// Problem constants (B=2, T=2048, C=2048, NH=16, L=128)
#define B_   2
#define T_   2048
#define C_   2048
#define NH_  16
#define L_   128
#define NKQ  2176   // L_ + NH_*L_
#define MTOK 4096   // B_*T_
#define SCALE_ 0.08838834764831845f           // 1/sqrt(128)
#define SCALE2_ 0.12753785792696073f          // SCALE_ * log2(e)

typedef short short8 __attribute__((ext_vector_type(8)));
typedef float f32x4  __attribute__((ext_vector_type(4)));

// async global->LDS, 16B per lane; LDS base must be wave-uniform.
#define GLD16(gp, lp) __builtin_amdgcn_global_load_lds(                      \
    (const __attribute__((address_space(1))) void*)(gp),                     \
    (__attribute__((address_space(3))) void*)(lp), 16, 0, 0)

__device__ __forceinline__ unsigned short f2bf(float f) {
  union { float f; unsigned u; } x; x.f = f;
  unsigned r = x.u + 0x7fffu + ((x.u >> 16) & 1u);   // RNE
  return (unsigned short)(r >> 16);
}

// ---------------- fp32 -> bf16 convert (n % 4 == 0) ----------------
__global__ void cvt_f32_bf16(const float* __restrict__ in,
                             unsigned short* __restrict__ out, int n) {
  int i = (blockIdx.x * blockDim.x + threadIdx.x) * 4;
  if (i >= n) return;
  float4 v = *(const float4*)(in + i);
  ushort4 o;
  o.x = f2bf(v.x); o.y = f2bf(v.y); o.z = f2bf(v.z); o.w = f2bf(v.w);
  *(ushort4*)(out + i) = o;
}

// ------------- transpose W[K][N] fp32 -> Wt[N][K] bf16 (x mul) -------------
__global__ void transpose_to_bf16(const float* __restrict__ W,
                                  unsigned short* __restrict__ Wt,
                                  int K, int N, float mul) {
  __shared__ float tile[32][33];
  int bx = blockIdx.x * 32;  // along N
  int by = blockIdx.y * 32;  // along K
  int tx = threadIdx.x, ty = threadIdx.y;
  #pragma unroll
  for (int i = 0; i < 4; i++)
    tile[ty + i * 8][tx] = W[(size_t)(by + ty + i * 8) * N + bx + tx];
  __syncthreads();
  #pragma unroll
  for (int i = 0; i < 4; i++)
    Wt[(size_t)(bx + ty + i * 8) * K + by + tx] = f2bf(tile[tx][ty + i * 8] * mul);
}

// ---- transpose latent cols of kq -> KlT[b][l][t] (bf16) ----
__global__ void transpose_lat(const unsigned short* __restrict__ kq,
                              unsigned short* __restrict__ KlT) {
  __shared__ unsigned short tile[32][33];
  int t0 = blockIdx.x * 32, l0 = blockIdx.y * 32, b = blockIdx.z;
  int tx = threadIdx.x, ty = threadIdx.y;
  #pragma unroll
  for (int i = 0; i < 4; i++)
    tile[ty + i * 8][tx] = kq[((size_t)b * T_ + t0 + ty + i * 8) * NKQ + l0 + tx];
  __syncthreads();
  #pragma unroll
  for (int i = 0; i < 4; i++)
    KlT[((size_t)b * L_ + l0 + ty + i * 8) * T_ + t0 + tx] = tile[tx][ty + i * 8];
}

// ---------------- concat bias [b_lat | scale*log2e*b_d] ----------------
__global__ void make_bias_cat(const float* __restrict__ b_lat,
                              const float* __restrict__ b_d,
                              float* __restrict__ out) {
  int i = blockIdx.x * blockDim.x + threadIdx.x;
  if (i < L_) out[i] = b_lat[i];
  else if (i < NKQ) out[i] = b_d[i - L_] * SCALE2_;
}

// ---------------- bf16 MFMA GEMM (m97 structure):  C = A @ Bt^T + bias ----------------
__global__ __launch_bounds__(256) void gemm_bt_bias(
    const unsigned short* __restrict__ A,   // [M][K] bf16
    const unsigned short* __restrict__ Bt,  // [N][K] bf16
    const float* __restrict__ bias,         // [N]
    unsigned short* __restrict__ Cb,        // bf16 out (or null)
    float* __restrict__ Cf,                 // fp32 out (or null)
    int M, int N, int K) {
  __shared__ __align__(16) unsigned short As[128 * 32];  // unpadded, BK=32
  __shared__ __align__(16) unsigned short Bs[128 * 32];
  const int tid  = threadIdx.x;
  const int wave = tid >> 6, lane = tid & 63;
  const int lcol = lane & 15, quad = lane >> 4;
  const int m0 = blockIdx.x * 128, n0 = blockIdx.y * 128;
  const int wm = (wave >> 1) * 64, wn = (wave & 1) * 64;
  const int lrow = lane >> 2, lchunk = (lane & 3) * 8;

  f32x4 acc[4][4];
  #pragma unroll
  for (int i = 0; i < 4; i++)
    #pragma unroll
    for (int j = 0; j < 4; j++) acc[i][j] = (f32x4){0.f, 0.f, 0.f, 0.f};

  for (int kc = 0; kc < K; kc += 32) {
    __syncthreads();
    {
      int rb = wave * 32;
      GLD16(&A [(size_t)(m0 + rb      + lrow) * K + kc + lchunk], &As[ rb       * 32]);
      GLD16(&A [(size_t)(m0 + rb + 16 + lrow) * K + kc + lchunk], &As[(rb + 16) * 32]);
      GLD16(&Bt[(size_t)(n0 + rb      + lrow) * K + kc + lchunk], &Bs[ rb       * 32]);
      GLD16(&Bt[(size_t)(n0 + rb + 16 + lrow) * K + kc + lchunk], &Bs[(rb + 16) * 32]);
    }
    __syncthreads();
    short8 af[4], bfr[4];
    #pragma unroll
    for (int i = 0; i < 4; i++)
      af[i] = *(const short8*)&As[(wm + i * 16 + lcol) * 32 + quad * 8];
    #pragma unroll
    for (int j = 0; j < 4; j++)
      bfr[j] = *(const short8*)&Bs[(wn + j * 16 + lcol) * 32 + quad * 8];
    #pragma unroll
    for (int i = 0; i < 4; i++)
      #pragma unroll
      for (int j = 0; j < 4; j++)
        acc[i][j] = __builtin_amdgcn_mfma_f32_16x16x32_bf16(af[i], bfr[j], acc[i][j], 0, 0, 0);
  }

  #pragma unroll
  for (int i = 0; i < 4; i++) {
    #pragma unroll
    for (int j = 0; j < 4; j++) {
      int col = n0 + wn + j * 16 + lcol;
      float bv = bias[col];
      #pragma unroll
      for (int r = 0; r < 4; r++) {
        int row = m0 + wm + i * 16 + quad * 4 + r;
        float v = acc[i][j][r] + bv;
        if (Cf) Cf[(size_t)row * N + col] = v;
        else    Cb[(size_t)row * N + col] = f2bf(v);
      }
    }
  }
}

// ---------------- fused causal MLA attention ----------------
// Block: 4 waves = 4 heads, 32 q-rows. s-tiles of 64.
// Grid 512 (1-D): n<256 -> heavy q-tile (63-qi), n>=256 -> light (qi), same
// (b,head-group) -> round-robin dispatch pairs heavy+light on each CU and
// 2 blocks/CU co-reside (48KB LDS) = 2 waves/SIMD for latency hiding.
// No-max softmax; scale*log2e folded into q; exp via native v_exp (2^x).
__global__ __launch_bounds__(256, 2) void attn_mla(
    const unsigned short* __restrict__ kq,   // [B*T][NKQ]
    const unsigned short* __restrict__ KlT,  // [B][L][T]
    unsigned short* __restrict__ y) {        // [B*T][NH*L]
  __shared__ __align__(16) unsigned short Kr[64 * 128];     // [s][l] swizzled
  __shared__ __align__(16) unsigned short Kt[128 * 64];     // [l][s] swizzled
  __shared__ __align__(16) unsigned short Pls[4 * 32 * 64]; // per-wave P, swizzled

  const int tid  = threadIdx.x;
  const int wave = tid >> 6, lane = tid & 63;
  const int lcol = lane & 15, quad = lane >> 4;
  const int n    = blockIdx.x;
  const int slot = n >> 8, c = n & 255;
  const int hg   = c >> 5, qi = c & 31;
  const int b    = hg >> 2;
  const int h    = (hg & 3) * 4 + wave;
  const int qt32 = slot ? qi : (63 - qi);    // 32-row q-tile index
  const size_t rowbase = (size_t)b * T_;
  const int q0 = qt32 * 32;
  unsigned short* Pw = &Pls[wave * 32 * 64];

  // Q fragments (A-layout m=lane&15, k=quad*8+j); scale*log2e pre-folded
  short8 qf[2][4];
  #pragma unroll
  for (int i = 0; i < 2; i++) {
    const unsigned short* qp = kq + (rowbase + q0 + i * 16 + lcol) * NKQ + L_ + h * L_;
    #pragma unroll
    for (int kc = 0; kc < 4; kc++)
      qf[i][kc] = *(const short8*)(qp + kc * 32 + quad * 8);
  }

  f32x4 acco[2][8];
  #pragma unroll
  for (int i = 0; i < 2; i++)
    #pragma unroll
    for (int ns = 0; ns < 8; ns++) acco[i][ns] = (f32x4){0.f, 0.f, 0.f, 0.f};
  float lsum[2][4];
  #pragma unroll
  for (int i = 0; i < 2; i++)
    #pragma unroll
    for (int r = 0; r < 4; r++) lsum[i][r] = 0.f;

  const int nt = (qt32 >> 1) + 1;
  for (int ts = 0; ts < nt; ts++) {
    const int s0 = ts * 64;
    __syncthreads();
    // stage Kr (64x128): swizzled source chunk -> LDS[row][c]=G[row][c^(row&7)]
    #pragma unroll
    for (int kk = 0; kk < 4; kk++) {
      int r0 = wave * 16 + kk * 4;
      int rg = r0 + (lane >> 4);
      int cl = ((lane & 15) ^ (rg & 7)) * 8;
      GLD16(kq + (rowbase + s0 + rg) * NKQ + cl, &Kr[r0 * 128]);
    }
    // stage Kt (128x64) from KlT
    #pragma unroll
    for (int kk = 0; kk < 4; kk++) {
      int r0 = wave * 32 + kk * 8;
      int rg = r0 + (lane >> 3);
      int cl = ((lane & 7) ^ (rg & 7)) * 8;
      GLD16(KlT + ((size_t)b * L_ + rg) * T_ + s0 + cl, &Kt[r0 * 64]);
    }
    __syncthreads();

    // S(32x64) = Q @ K^T
    f32x4 accs[2][4];
    #pragma unroll
    for (int i = 0; i < 2; i++)
      #pragma unroll
      for (int ns = 0; ns < 4; ns++) accs[i][ns] = (f32x4){0.f, 0.f, 0.f, 0.f};
    #pragma unroll
    for (int kc = 0; kc < 4; kc++)
      #pragma unroll
      for (int ns = 0; ns < 4; ns++) {
        short8 bfrag = *(const short8*)&Kr[(ns * 16 + lcol) * 128 +
                                           (((kc * 4 + quad) ^ (lcol & 7)) * 8)];
        #pragma unroll
        for (int i = 0; i < 2; i++)
          accs[i][ns] = __builtin_amdgcn_mfma_f32_16x16x32_bf16(qf[i][kc], bfrag, accs[i][ns], 0, 0, 0);
      }

    // p = 2^s (log2e folded); truncate to bf16, lsum from truncated value
    const bool diag = (ts == nt - 1);
    #pragma unroll
    for (int i = 0; i < 2; i++)
      #pragma unroll
      for (int ns = 0; ns < 4; ns++)
        #pragma unroll
        for (int r = 0; r < 4; r++) {
          float v = accs[i][ns][r];
          int sg = ns * 16 + lcol;
          int qg = (qt32 & 1) * 32 + i * 16 + quad * 4 + r;
          if (diag && sg > qg) v = -1e30f;
          float e = __builtin_amdgcn_exp2f(v);
          unsigned eu = __float_as_uint(e) & 0xffff0000u;
          lsum[i][r] += __uint_as_float(eu);
          int row = i * 16 + quad * 4 + r;
          int col = ns * 16 + lcol;
          int phys = ((col >> 3) ^ (row & 7));
          Pw[row * 64 + phys * 8 + (col & 7)] = (unsigned short)(eu >> 16);
        }

    // O(32x128) += P(32x64) @ K(64x128)
    #pragma unroll
    for (int kc2 = 0; kc2 < 2; kc2++) {
      short8 pa[2];
      #pragma unroll
      for (int i = 0; i < 2; i++)
        pa[i] = *(const short8*)&Pw[(i * 16 + lcol) * 64 +
                                    (((kc2 * 4 + quad) ^ (lcol & 7)) * 8)];
      #pragma unroll
      for (int ns = 0; ns < 8; ns++) {
        short8 bfrag = *(const short8*)&Kt[(ns * 16 + lcol) * 64 +
                                           (((kc2 * 4 + quad) ^ (lcol & 7)) * 8)];
        #pragma unroll
        for (int i = 0; i < 2; i++)
          acco[i][ns] = __builtin_amdgcn_mfma_f32_16x16x32_bf16(pa[i], bfrag, acco[i][ns], 0, 0, 0);
      }
    }
  }

  // reduce row sums across the 16 lcol lanes (once)
  #pragma unroll
  for (int i = 0; i < 2; i++)
    #pragma unroll
    for (int r = 0; r < 4; r++) {
      float s = lsum[i][r];
      #pragma unroll
      for (int off = 1; off < 16; off <<= 1) s += __shfl_xor(s, off, 64);
      lsum[i][r] = 1.f / s;
    }

  // write y
  #pragma unroll
  for (int i = 0; i < 2; i++)
    #pragma unroll
    for (int ns = 0; ns < 8; ns++)
      #pragma unroll
      for (int r = 0; r < 4; r++) {
        int qg = q0 + i * 16 + quad * 4 + r;
        y[(rowbase + qg) * (NH_ * L_) + h * L_ + ns * 16 + lcol] =
            f2bf(acco[i][ns][r] * lsum[i][r]);
      }
}

extern "C" void kernel_launch(void* const* d_in, const int* in_sizes, int n_in,
                              void* d_out, int out_size, void* d_ws, size_t ws_size,
                              hipStream_t stream) {
  const float* x      = (const float*)d_in[0];
  const float* W_lat  = (const float*)d_in[1];
  const float* b_lat  = (const float*)d_in[2];
  const float* W_d    = (const float*)d_in[3];
  const float* b_d    = (const float*)d_in[4];
  const float* W_proj = (const float*)d_in[5];
  const float* b_proj = (const float*)d_in[6];
  float* out = (float*)d_out;

  // workspace layout (bf16 buffers, 16B aligned)
  unsigned short* x_bf   = (unsigned short*)d_ws;                  // [4096][2048]
  unsigned short* BtCat  = x_bf   + (size_t)MTOK * C_;             // [2176][2048]
  unsigned short* WprojT = BtCat  + (size_t)NKQ * C_;              // [2048][2048]
  unsigned short* kqbuf  = WprojT + (size_t)C_ * (NH_ * L_);       // [4096][2176]
  unsigned short* ybuf   = kqbuf  + (size_t)MTOK * NKQ;            // [4096][2048]
  unsigned short* KlT    = ybuf   + (size_t)MTOK * (NH_ * L_);     // [2][128][2048]
  float*          biascat = (float*)(KlT + (size_t)B_ * L_ * T_);  // [2176]

  // 1. x -> bf16
  cvt_f32_bf16<<<(MTOK * C_) / 1024, 256, 0, stream>>>(x, x_bf, MTOK * C_);
  // 2. weights -> transposed bf16 (Bt layout); fold scale*log2e into W_d
  transpose_to_bf16<<<dim3(L_ / 32, C_ / 32), dim3(32, 8), 0, stream>>>(W_lat, BtCat, C_, L_, 1.f);
  transpose_to_bf16<<<dim3((NH_ * L_) / 32, C_ / 32), dim3(32, 8), 0, stream>>>(
      W_d, BtCat + (size_t)L_ * C_, C_, NH_ * L_, SCALE2_);
  transpose_to_bf16<<<dim3(C_ / 32, (NH_ * L_) / 32), dim3(32, 8), 0, stream>>>(
      W_proj, WprojT, NH_ * L_, C_, 1.f);
  make_bias_cat<<<(NKQ + 255) / 256, 256, 0, stream>>>(b_lat, b_d, biascat);
  // 3. kq = x @ [W_lat | scale*log2e*W_d] + bias (bf16 out)
  gemm_bt_bias<<<dim3(MTOK / 128, NKQ / 128), 256, 0, stream>>>(
      x_bf, BtCat, biascat, kqbuf, nullptr, MTOK, NKQ, C_);
  // 4. latent transpose for PV staging
  transpose_lat<<<dim3(T_ / 32, L_ / 32, B_), dim3(32, 8), 0, stream>>>(kqbuf, KlT);
  // 5. causal MLA attention (512 balanced blocks)
  attn_mla<<<512, 256, 0, stream>>>(kqbuf, KlT, ybuf);
  // 6. out = y @ W_proj + b_proj (fp32 out)
  gemm_bt_bias<<<dim3(MTOK / 128, C_ / 128), 256, 0, stream>>>(
      ybuf, WprojT, b_proj, nullptr, out, MTOK, C_, C_);
}

// Round 5
// 308.227 us; speedup vs baseline: 2.0567x; 1.0039x over previous
//
#include <hip/hip_runtime.h>
#include <hip/hip_bf16.h>

// Problem constants (B=2, T=2048, C=2048, NH=16, L=128)
#define B_   2
#define T_   2048
#define C_   2048
#define NH_  16
#define L_   128
#define NKQ  2176   // L_ + NH_*L_
#define MTOK 4096   // B_*T_
#define SCALE_ 0.08838834764831845f           // 1/sqrt(128)
#define SCALE2_ 0.12753785792696073f          // SCALE_ * log2(e)

typedef short short8 __attribute__((ext_vector_type(8)));
typedef float f32x4  __attribute__((ext_vector_type(4)));

// async global->LDS, 16B per lane; LDS base must be wave-uniform.
#define GLD16(gp, lp) __builtin_amdgcn_global_load_lds(                      \
    (const __attribute__((address_space(1))) void*)(gp),                     \
    (__attribute__((address_space(3))) void*)(lp), 16, 0, 0)

__device__ __forceinline__ unsigned short f2bf(float f) {
  union { float f; unsigned u; } x; x.f = f;
  unsigned r = x.u + 0x7fffu + ((x.u >> 16) & 1u);   // RNE
  return (unsigned short)(r >> 16);
}

// ---------------- fp32 -> bf16 convert (n % 4 == 0) ----------------
__global__ void cvt_f32_bf16(const float* __restrict__ in,
                             unsigned short* __restrict__ out, int n) {
  int i = (blockIdx.x * blockDim.x + threadIdx.x) * 4;
  if (i >= n) return;
  float4 v = *(const float4*)(in + i);
  ushort4 o;
  o.x = f2bf(v.x); o.y = f2bf(v.y); o.z = f2bf(v.z); o.w = f2bf(v.w);
  *(ushort4*)(out + i) = o;
}

// ------------- transpose W[K][N] fp32 -> Wt[N][K] bf16 (x mul) -------------
__global__ void transpose_to_bf16(const float* __restrict__ W,
                                  unsigned short* __restrict__ Wt,
                                  int K, int N, float mul) {
  __shared__ float tile[32][33];
  int bx = blockIdx.x * 32;  // along N
  int by = blockIdx.y * 32;  // along K
  int tx = threadIdx.x, ty = threadIdx.y;
  #pragma unroll
  for (int i = 0; i < 4; i++)
    tile[ty + i * 8][tx] = W[(size_t)(by + ty + i * 8) * N + bx + tx];
  __syncthreads();
  #pragma unroll
  for (int i = 0; i < 4; i++)
    Wt[(size_t)(bx + ty + i * 8) * K + by + tx] = f2bf(tile[tx][ty + i * 8] * mul);
}

// ---- transpose latent cols of kq -> KlT[b][l][t] (bf16) ----
__global__ void transpose_lat(const unsigned short* __restrict__ kq,
                              unsigned short* __restrict__ KlT) {
  __shared__ unsigned short tile[32][33];
  int t0 = blockIdx.x * 32, l0 = blockIdx.y * 32, b = blockIdx.z;
  int tx = threadIdx.x, ty = threadIdx.y;
  #pragma unroll
  for (int i = 0; i < 4; i++)
    tile[ty + i * 8][tx] = kq[((size_t)b * T_ + t0 + ty + i * 8) * NKQ + l0 + tx];
  __syncthreads();
  #pragma unroll
  for (int i = 0; i < 4; i++)
    KlT[((size_t)b * L_ + l0 + ty + i * 8) * T_ + t0 + tx] = tile[tx][ty + i * 8];
}

// ---------------- concat bias [b_lat | scale*log2e*b_d] ----------------
__global__ void make_bias_cat(const float* __restrict__ b_lat,
                              const float* __restrict__ b_d,
                              float* __restrict__ out) {
  int i = blockIdx.x * blockDim.x + threadIdx.x;
  if (i < L_) out[i] = b_lat[i];
  else if (i < NKQ) out[i] = b_d[i - L_] * SCALE2_;
}

// ---------------- bf16 MFMA GEMM (m97 structure):  C = A @ Bt^T + bias ----------------
__global__ __launch_bounds__(256) void gemm_bt_bias(
    const unsigned short* __restrict__ A,   // [M][K] bf16
    const unsigned short* __restrict__ Bt,  // [N][K] bf16
    const float* __restrict__ bias,         // [N]
    unsigned short* __restrict__ Cb,        // bf16 out (or null)
    float* __restrict__ Cf,                 // fp32 out (or null)
    int M, int N, int K) {
  __shared__ __align__(16) unsigned short As[128 * 32];  // unpadded, BK=32
  __shared__ __align__(16) unsigned short Bs[128 * 32];
  const int tid  = threadIdx.x;
  const int wave = tid >> 6, lane = tid & 63;
  const int lcol = lane & 15, quad = lane >> 4;
  const int m0 = blockIdx.x * 128, n0 = blockIdx.y * 128;
  const int wm = (wave >> 1) * 64, wn = (wave & 1) * 64;
  const int lrow = lane >> 2, lchunk = (lane & 3) * 8;

  f32x4 acc[4][4];
  #pragma unroll
  for (int i = 0; i < 4; i++)
    #pragma unroll
    for (int j = 0; j < 4; j++) acc[i][j] = (f32x4){0.f, 0.f, 0.f, 0.f};

  for (int kc = 0; kc < K; kc += 32) {
    __syncthreads();
    {
      int rb = wave * 32;
      GLD16(&A [(size_t)(m0 + rb      + lrow) * K + kc + lchunk], &As[ rb       * 32]);
      GLD16(&A [(size_t)(m0 + rb + 16 + lrow) * K + kc + lchunk], &As[(rb + 16) * 32]);
      GLD16(&Bt[(size_t)(n0 + rb      + lrow) * K + kc + lchunk], &Bs[ rb       * 32]);
      GLD16(&Bt[(size_t)(n0 + rb + 16 + lrow) * K + kc + lchunk], &Bs[(rb + 16) * 32]);
    }
    __syncthreads();
    short8 af[4], bfr[4];
    #pragma unroll
    for (int i = 0; i < 4; i++)
      af[i] = *(const short8*)&As[(wm + i * 16 + lcol) * 32 + quad * 8];
    #pragma unroll
    for (int j = 0; j < 4; j++)
      bfr[j] = *(const short8*)&Bs[(wn + j * 16 + lcol) * 32 + quad * 8];
    #pragma unroll
    for (int i = 0; i < 4; i++)
      #pragma unroll
      for (int j = 0; j < 4; j++)
        acc[i][j] = __builtin_amdgcn_mfma_f32_16x16x32_bf16(af[i], bfr[j], acc[i][j], 0, 0, 0);
  }

  #pragma unroll
  for (int i = 0; i < 4; i++) {
    #pragma unroll
    for (int j = 0; j < 4; j++) {
      int col = n0 + wn + j * 16 + lcol;
      float bv = bias[col];
      #pragma unroll
      for (int r = 0; r < 4; r++) {
        int row = m0 + wm + i * 16 + quad * 4 + r;
        float v = acc[i][j][r] + bv;
        if (Cf) Cf[(size_t)row * N + col] = v;
        else    Cb[(size_t)row * N + col] = f2bf(v);
      }
    }
  }
}

// ---------------- fused causal MLA attention (double-buffered K staging) ----------------
// Block: 4 waves = 4 heads, 32 q-rows. s-tiles of 64, K tiles double-buffered:
//   stage(0); loop: barrier; stage(ts+1 -> other buf); compute(ts)
// so the barrier's vmcnt drain waits on loads issued a full compute-phase ago.
// NOTE (R4 bug): the staging swizzle XOR must use the ACTUAL row&7 of each
// sub-load (rows differ by 4 between kk's) — compute it per kk, don't hoist.
// Grid 512: n<256 heavy tile (63-qi), n>=256 light (qi) -> heavy+light pair per CU.
// No-max softmax; scale*log2e folded into q; exp via v_exp2.
__global__ __launch_bounds__(256, 2) void attn_mla(
    const unsigned short* __restrict__ kq,   // [B*T][NKQ]
    const unsigned short* __restrict__ KlT,  // [B][L][T]
    unsigned short* __restrict__ y) {        // [B*T][NH*L]
  __shared__ __align__(16) unsigned short Kr[2][64 * 128];   // [s][l] swizzled
  __shared__ __align__(16) unsigned short Kt[2][128 * 64];   // [l][s] swizzled
  __shared__ __align__(16) unsigned short Pls[4][32 * 64];   // per-wave P, swizzled

  const int tid  = threadIdx.x;
  const int wave = tid >> 6, lane = tid & 63;
  const int lcol = lane & 15, quad = lane >> 4;
  const int n    = blockIdx.x;
  const int slot = n >> 8, c = n & 255;
  const int hg   = c >> 5, qi = c & 31;
  const int b    = hg >> 2;
  const int h    = (hg & 3) * 4 + wave;
  const int qt32 = slot ? qi : (63 - qi);    // 32-row q-tile index
  const size_t rowbase = (size_t)b * T_;
  const int q0 = qt32 * 32;
  unsigned short* Pw = &Pls[wave][0];

  // Q fragments (A-layout m=lane&15, k=quad*8+j); scale*log2e pre-folded
  short8 qf[2][4];
  #pragma unroll
  for (int i = 0; i < 2; i++) {
    const unsigned short* qp = kq + (rowbase + q0 + i * 16 + lcol) * NKQ + L_ + h * L_;
    #pragma unroll
    for (int kc = 0; kc < 4; kc++)
      qf[i][kc] = *(const short8*)(qp + kc * 32 + quad * 8);
  }

  f32x4 acco[2][8];
  #pragma unroll
  for (int i = 0; i < 2; i++)
    #pragma unroll
    for (int ns = 0; ns < 8; ns++) acco[i][ns] = (f32x4){0.f, 0.f, 0.f, 0.f};
  float lsum[2][4];
  #pragma unroll
  for (int i = 0; i < 2; i++)
    #pragma unroll
    for (int r = 0; r < 4; r++) lsum[i][r] = 0.f;

  const int nt = (qt32 >> 1) + 1;

  // prologue: stage tile 0 into buffer 0 (swizzle computed per sub-load!)
  #pragma unroll
  for (int kk = 0; kk < 4; kk++) {
    int r0 = wave * 16 + kk * 4;
    int rg = r0 + (lane >> 4);
    int cl = ((lane & 15) ^ (rg & 7)) * 8;
    GLD16(kq + (rowbase + rg) * NKQ + cl, &Kr[0][r0 * 128]);
  }
  #pragma unroll
  for (int kk = 0; kk < 4; kk++) {
    int r0 = wave * 32 + kk * 8;
    int rg = r0 + (lane >> 3);
    int cl = ((lane & 7) ^ (rg & 7)) * 8;
    GLD16(KlT + ((size_t)b * L_ + rg) * T_ + cl, &Kt[0][r0 * 64]);
  }

  for (int ts = 0; ts < nt; ts++) {
    const int cur = ts & 1;
    __syncthreads();  // drains stage(ts) [issued one full phase ago] + guards buf reuse

    if (ts + 1 < nt) {  // prefetch next tile into the other buffer
      const int s1 = (ts + 1) * 64;
      #pragma unroll
      for (int kk = 0; kk < 4; kk++) {
        int r0 = wave * 16 + kk * 4;
        int rg = r0 + (lane >> 4);
        int cl = ((lane & 15) ^ (rg & 7)) * 8;
        GLD16(kq + (rowbase + s1 + rg) * NKQ + cl, &Kr[cur ^ 1][r0 * 128]);
      }
      #pragma unroll
      for (int kk = 0; kk < 4; kk++) {
        int r0 = wave * 32 + kk * 8;
        int rg = r0 + (lane >> 3);
        int cl = ((lane & 7) ^ (rg & 7)) * 8;
        GLD16(KlT + ((size_t)b * L_ + rg) * T_ + s1 + cl, &Kt[cur ^ 1][r0 * 64]);
      }
    }

    const unsigned short* Krc = &Kr[cur][0];
    const unsigned short* Ktc = &Kt[cur][0];

    // S(32x64) = Q @ K^T
    f32x4 accs[2][4];
    #pragma unroll
    for (int i = 0; i < 2; i++)
      #pragma unroll
      for (int ns = 0; ns < 4; ns++) accs[i][ns] = (f32x4){0.f, 0.f, 0.f, 0.f};
    #pragma unroll
    for (int kc = 0; kc < 4; kc++)
      #pragma unroll
      for (int ns = 0; ns < 4; ns++) {
        short8 bfrag = *(const short8*)&Krc[(ns * 16 + lcol) * 128 +
                                            (((kc * 4 + quad) ^ (lcol & 7)) * 8)];
        #pragma unroll
        for (int i = 0; i < 2; i++)
          accs[i][ns] = __builtin_amdgcn_mfma_f32_16x16x32_bf16(qf[i][kc], bfrag, accs[i][ns], 0, 0, 0);
      }

    // p = 2^s (log2e folded); truncate to bf16, lsum from truncated value
    const bool diag = (ts == nt - 1);
    #pragma unroll
    for (int i = 0; i < 2; i++)
      #pragma unroll
      for (int ns = 0; ns < 4; ns++)
        #pragma unroll
        for (int r = 0; r < 4; r++) {
          float v = accs[i][ns][r];
          int sg = ns * 16 + lcol;
          int qg = (qt32 & 1) * 32 + i * 16 + quad * 4 + r;
          if (diag && sg > qg) v = -1e30f;
          float e = __builtin_amdgcn_exp2f(v);
          unsigned eu = __float_as_uint(e) & 0xffff0000u;
          lsum[i][r] += __uint_as_float(eu);
          int row = i * 16 + quad * 4 + r;
          int col = ns * 16 + lcol;
          int phys = ((col >> 3) ^ (row & 7));
          Pw[row * 64 + phys * 8 + (col & 7)] = (unsigned short)(eu >> 16);
        }

    // O(32x128) += P(32x64) @ K(64x128)   (Pw is wave-private: no barrier needed)
    #pragma unroll
    for (int kc2 = 0; kc2 < 2; kc2++) {
      short8 pa[2];
      #pragma unroll
      for (int i = 0; i < 2; i++)
        pa[i] = *(const short8*)&Pw[(i * 16 + lcol) * 64 +
                                    (((kc2 * 4 + quad) ^ (lcol & 7)) * 8)];
      #pragma unroll
      for (int ns = 0; ns < 8; ns++) {
        short8 bfrag = *(const short8*)&Ktc[(ns * 16 + lcol) * 64 +
                                            (((kc2 * 4 + quad) ^ (lcol & 7)) * 8)];
        #pragma unroll
        for (int i = 0; i < 2; i++)
          acco[i][ns] = __builtin_amdgcn_mfma_f32_16x16x32_bf16(pa[i], bfrag, acco[i][ns], 0, 0, 0);
      }
    }
  }

  // reduce row sums across the 16 lcol lanes (once)
  #pragma unroll
  for (int i = 0; i < 2; i++)
    #pragma unroll
    for (int r = 0; r < 4; r++) {
      float s = lsum[i][r];
      #pragma unroll
      for (int off = 1; off < 16; off <<= 1) s += __shfl_xor(s, off, 64);
      lsum[i][r] = 1.f / s;
    }

  // write y
  #pragma unroll
  for (int i = 0; i < 2; i++)
    #pragma unroll
    for (int ns = 0; ns < 8; ns++)
      #pragma unroll
      for (int r = 0; r < 4; r++) {
        int qg = q0 + i * 16 + quad * 4 + r;
        y[(rowbase + qg) * (NH_ * L_) + h * L_ + ns * 16 + lcol] =
            f2bf(acco[i][ns][r] * lsum[i][r]);
      }
}

extern "C" void kernel_launch(void* const* d_in, const int* in_sizes, int n_in,
                              void* d_out, int out_size, void* d_ws, size_t ws_size,
                              hipStream_t stream) {
  const float* x      = (const float*)d_in[0];
  const float* W_lat  = (const float*)d_in[1];
  const float* b_lat  = (const float*)d_in[2];
  const float* W_d    = (const float*)d_in[3];
  const float* b_d    = (const float*)d_in[4];
  const float* W_proj = (const float*)d_in[5];
  const float* b_proj = (const float*)d_in[6];
  float* out = (float*)d_out;

  // workspace layout (bf16 buffers, 16B aligned)
  unsigned short* x_bf   = (unsigned short*)d_ws;                  // [4096][2048]
  unsigned short* BtCat  = x_bf   + (size_t)MTOK * C_;             // [2176][2048]
  unsigned short* WprojT = BtCat  + (size_t)NKQ * C_;              // [2048][2048]
  unsigned short* kqbuf  = WprojT + (size_t)C_ * (NH_ * L_);       // [4096][2176]
  unsigned short* ybuf   = kqbuf  + (size_t)MTOK * NKQ;            // [4096][2048]
  unsigned short* KlT    = ybuf   + (size_t)MTOK * (NH_ * L_);     // [2][128][2048]
  float*          biascat = (float*)(KlT + (size_t)B_ * L_ * T_);  // [2176]

  // 1. x -> bf16
  cvt_f32_bf16<<<(MTOK * C_) / 1024, 256, 0, stream>>>(x, x_bf, MTOK * C_);
  // 2. weights -> transposed bf16 (Bt layout); fold scale*log2e into W_d
  transpose_to_bf16<<<dim3(L_ / 32, C_ / 32), dim3(32, 8), 0, stream>>>(W_lat, BtCat, C_, L_, 1.f);
  transpose_to_bf16<<<dim3((NH_ * L_) / 32, C_ / 32), dim3(32, 8), 0, stream>>>(
      W_d, BtCat + (size_t)L_ * C_, C_, NH_ * L_, SCALE2_);
  transpose_to_bf16<<<dim3(C_ / 32, (NH_ * L_) / 32), dim3(32, 8), 0, stream>>>(
      W_proj, WprojT, NH_ * L_, C_, 1.f);
  make_bias_cat<<<(NKQ + 255) / 256, 256, 0, stream>>>(b_lat, b_d, biascat);
  // 3. kq = x @ [W_lat | scale*log2e*W_d] + bias (bf16 out)
  gemm_bt_bias<<<dim3(MTOK / 128, NKQ / 128), 256, 0, stream>>>(
      x_bf, BtCat, biascat, kqbuf, nullptr, MTOK, NKQ, C_);
  // 4. latent transpose for PV staging
  transpose_lat<<<dim3(T_ / 32, L_ / 32, B_), dim3(32, 8), 0, stream>>>(kqbuf, KlT);
  // 5. causal MLA attention (512 balanced blocks, double-buffered)
  attn_mla<<<512, 256, 0, stream>>>(kqbuf, KlT, ybuf);
  // 6. out = y @ W_proj + b_proj (fp32 out)
  gemm_bt_bias<<<dim3(MTOK / 128, C_ / 128), 256, 0, stream>>>(
      ybuf, WprojT, b_proj, nullptr, out, MTOK, C_, C_);
}